// Round 1
// baseline (7231.732 us; speedup 1.0000x reference)
//
#include <hip/hip_runtime.h>

#define Bb 256
#define Tt 256
#define Dd 64
#define Hh 512
#define BH (Bb*Hh)
#define NBLK 256

typedef _Float16 half8 __attribute__((ext_vector_type(8)));
typedef float floatx4 __attribute__((ext_vector_type(4)));

__device__ __forceinline__ float sigm(float x) { return 1.0f/(1.0f + __expf(-x)); }
__device__ __forceinline__ float tanh_(float x) {
  if (x >  15.0f) return  1.0f;
  if (x < -15.0f) return -1.0f;
  float e = __expf(2.0f*x);
  return (e - 1.0f)/(e + 1.0f);
}

// init: transpose+convert x [B,T,D]fp32 -> xf16 [T,B,D], zero h buffers, zero barrier
__global__ void init_kernel(const float* __restrict__ x,
                            _Float16* __restrict__ xf16,
                            _Float16* __restrict__ hz,
                            unsigned* __restrict__ bar) {
  if (blockIdx.x == 0 && threadIdx.x == 0) *bar = 0u;
  const int NX = Bb*Tt*Dd;          // 4194304
  const int NZ = 4*BH;              // 524288
  for (int j = blockIdx.x*blockDim.x + threadIdx.x; j < NX + NZ; j += gridDim.x*blockDim.x) {
    if (j < NX) {
      int t = j >> 14, r = j & 16383;
      int b = r >> 6, d = r & 63;
      xf16[j] = (_Float16)x[(b << 14) + (t << 6) + d];
    } else {
      hz[j - NX] = (_Float16)0.0f;
    }
  }
}

__device__ __forceinline__ void grid_barrier(unsigned* bar, unsigned target) {
  __syncthreads();
  if (threadIdx.x == 0) {
    __threadfence();  // device-scope release of this block's h stores (L2 writeback on MI355X)
    __hip_atomic_fetch_add(bar, 1u, __ATOMIC_RELEASE, __HIP_MEMORY_SCOPE_AGENT);
    while (__hip_atomic_load(bar, __ATOMIC_RELAXED, __HIP_MEMORY_SCOPE_AGENT) < target)
      __builtin_amdgcn_s_sleep(1);
    __builtin_amdgcn_fence(__ATOMIC_ACQUIRE, "agent");  // invalidate stale cached h
  }
  __syncthreads();
}

#define GSTEP(APTR0, APTR1, kofs, klds)                                      \
  {                                                                          \
    half8 a0 = *(const half8*)((APTR0) + (kofs));                            \
    half8 a1 = *(const half8*)((APTR1) + (kofs));                            \
    half8 b0 = *(const half8*)(b0base + (((klds) + 8*kg) ^ xr));             \
    half8 b1 = *(const half8*)(b1base + (((klds) + 8*kg) ^ xr));             \
    acc00 = __builtin_amdgcn_mfma_f32_16x16x32_f16(a0, b0, acc00, 0, 0, 0);  \
    acc01 = __builtin_amdgcn_mfma_f32_16x16x32_f16(a0, b1, acc01, 0, 0, 0);  \
    acc10 = __builtin_amdgcn_mfma_f32_16x16x32_f16(a1, b0, acc10, 0, 0, 0);  \
    acc11 = __builtin_amdgcn_mfma_f32_16x16x32_f16(a1, b1, acc11, 0, 0, 0);  \
  }

__global__ void __launch_bounds__(256)
lstm_fused(const _Float16* __restrict__ xf16,
           _Float16* __restrict__ hbufs,      // h1[2 x BH] then h2[2 x BH]
           unsigned* __restrict__ bar,
           const float* __restrict__ Wih0, const float* __restrict__ Whh0,
           const float* __restrict__ bih0, const float* __restrict__ bhh0,
           const float* __restrict__ Wih1, const float* __restrict__ Whh1,
           const float* __restrict__ bih1, const float* __restrict__ bhh1,
           const float* __restrict__ fcw,  const float* __restrict__ fcb,
           float* __restrict__ out)
{
  __shared__ _Float16 lds[32*1024];   // 64 KiB: W slice, rows=32 gate-cols, pitch 1024, k XOR-swizzled

  const int tid  = threadIdx.x;
  const int bid  = blockIdx.x;
  const int lb   = bid >> 7;          // 0: layer0, 1: layer1
  const int lbid = bid & 127;
  const int cgi  = lbid >> 1;         // 64 col-groups (8 h-cols each)
  const int rgi  = lbid & 1;          // 2 row-groups (128 rows each)
  const int hc0  = cgi * 8;
  const int r0   = rgi * 128;

  _Float16* h1buf = hbufs;
  _Float16* h2buf = hbufs + 2*BH;

  // ---- preload W slice (fp32 -> fp16), swizzled ----
  {
    const float* Whh = lb ? Whh1 : Whh0;
    const float* Wih = lb ? Wih1 : Wih0;
    const int Kin = lb ? 512 : 64;
    for (int gr = 0; gr < 32; ++gr) {
      const int gate = gr >> 3, hcc = gr & 7;
      const int wrow = gate*512 + hc0 + hcc;
      const int swz = (gr & 7) << 3;
      const float* s0 = Whh + (size_t)wrow*512;
      for (int k = tid; k < 512; k += 256)
        lds[gr*1024 + (k ^ swz)] = (_Float16)s0[k];
      const float* s1 = Wih + (size_t)wrow*Kin;
      for (int k2 = tid; k2 < Kin; k2 += 256)
        lds[gr*1024 + ((512 + k2) ^ swz)] = (_Float16)s1[k2];
    }
  }
  __syncthreads();

  // lane geometry
  const int w    = tid >> 6;
  const int lane = tid & 63;
  const int kg   = lane >> 4;      // k-group 0..3
  const int n15  = lane & 15;
  const bool lo  = (n15 < 8);
  const int hcg  = hc0 + (n15 & 7);
  const int xr   = (n15 & 7) << 3; // B-read swizzle (gr&7)<<3
  const int arow0 = r0 + w*32 + n15;
  const int arow1 = arow0 + 16;

  const float* bi = lb ? bih1 : bih0;
  const float* bh = lb ? bhh1 : bhh0;
  const float biasA = lo ? (bi[hcg]      + bh[hcg])      : (bi[512+hcg]  + bh[512+hcg]);   // i | f
  const float biasB = lo ? (bi[1024+hcg] + bh[1024+hcg]) : (bi[1536+hcg] + bh[1536+hcg]);  // g | o

  float cst[2][4] = {{0.f,0.f,0.f,0.f},{0.f,0.f,0.f,0.f}};

  _Float16* const mybuf = lb ? h2buf : h1buf;
  const _Float16* const b0base = lds + n15*1024;
  const _Float16* const b1base = lds + (16+n15)*1024;

  for (int i = 0; i <= Tt; ++i) {
    const bool active = lb ? (i >= 1) : (i < Tt);
    if (active) {
      const int pprev = (i+1) & 1, pcur = i & 1;
      const _Float16* hprev = mybuf + (size_t)pprev*BH;
      const _Float16* src2  = lb ? (h1buf + (size_t)pprev*BH) : (xf16 + (size_t)i*(Bb*Dd));
      const int s2s = lb ? 512 : 64;

      floatx4 acc00 = {0.f,0.f,0.f,0.f}, acc01 = {0.f,0.f,0.f,0.f};
      floatx4 acc10 = {0.f,0.f,0.f,0.f}, acc11 = {0.f,0.f,0.f,0.f};

      const _Float16* a0p = hprev + (size_t)arow0*512 + 8*kg;
      const _Float16* a1p = hprev + (size_t)arow1*512 + 8*kg;
      #pragma unroll 4
      for (int ks = 0; ks < 16; ++ks) GSTEP(a0p, a1p, ks*32, ks*32)

      const _Float16* c0p = src2 + (size_t)arow0*s2s + 8*kg;
      const _Float16* c1p = src2 + (size_t)arow1*s2s + 8*kg;
      if (lb) {
        #pragma unroll 4
        for (int ks = 0; ks < 16; ++ks) GSTEP(c0p, c1p, ks*32, 512 + ks*32)
      } else {
        GSTEP(c0p, c1p, 0, 512)
        GSTEP(c0p, c1p, 32, 544)
      }

      // gate update: lo lanes hold i,g; hi lanes hold f,o (same h-col via lane^8)
      _Float16* hcur = mybuf + (size_t)pcur*BH;
      #pragma unroll
      for (int rs = 0; rs < 2; ++rs) {
        const floatx4 vA = rs ? acc10 : acc00;
        const floatx4 vB = rs ? acc11 : acc01;
        #pragma unroll
        for (int rr = 0; rr < 4; ++rr) {
          const float pA = vA[rr] + biasA;
          const float pB = vB[rr] + biasB;
          const float v1 = sigm(pA);                        // sig(i) | sig(f)
          const float v2 = lo ? tanh_(pB) : sigm(pB);       // tanh(g) | sig(o)
          const float fs  = __shfl_xor(v1, 8, 64);          // lo gets sig(f)
          const float os_ = __shfl_xor(v2, 8, 64);          // lo gets sig(o)
          if (lo) {
            const float c = fs * cst[rs][rr] + v1 * v2;
            cst[rs][rr] = c;
            const float hval = os_ * tanh_(c);
            const int row = r0 + w*32 + rs*16 + kg*4 + rr;
            hcur[(size_t)row*512 + hcg] = (_Float16)hval;
          }
        }
      }
    }
    grid_barrier(bar, (unsigned)(NBLK * (i + 1)));
  }

  // FC: out[b] = h2[T-1][b,:] . fcw + fcb   (h2 final parity = 0 since T even)
  if (bid == 0) {
    const int b = tid;
    const _Float16* h2 = h2buf;
    float acc = fcb[0];
    #pragma unroll 8
    for (int k = 0; k < 512; ++k)
      acc += (float)h2[(size_t)b*512 + k] * fcw[k];
    out[b] = acc;
  }
}

extern "C" void kernel_launch(void* const* d_in, const int* in_sizes, int n_in,
                              void* d_out, int out_size, void* d_ws, size_t ws_size,
                              hipStream_t stream) {
  const float* x    = (const float*)d_in[0];
  const float* Wih0 = (const float*)d_in[1];
  const float* Whh0 = (const float*)d_in[2];
  const float* bih0 = (const float*)d_in[3];
  const float* bhh0 = (const float*)d_in[4];
  const float* Wih1 = (const float*)d_in[5];
  const float* Whh1 = (const float*)d_in[6];
  const float* bih1 = (const float*)d_in[7];
  const float* bhh1 = (const float*)d_in[8];
  const float* fcw  = (const float*)d_in[9];
  const float* fcb  = (const float*)d_in[10];
  float* out = (float*)d_out;

  _Float16* xf16  = (_Float16*)d_ws;                         // 8,388,608 B
  _Float16* hbufs = xf16 + (size_t)Bb*Tt*Dd;                 // 1,048,576 B (h1 x2, h2 x2)
  unsigned* bar   = (unsigned*)(hbufs + (size_t)4*BH);       // 4 B

  hipLaunchKernelGGL(init_kernel, dim3(1024), dim3(256), 0, stream, x, xf16, hbufs, bar);

  hipLaunchKernelGGL(lstm_fused, dim3(NBLK), dim3(256), 0, stream,
                     (const _Float16*)xf16, hbufs, bar,
                     Wih0, Whh0, bih0, bhh0, Wih1, Whh1, bih1, bhh1, fcw, fcb, out);
}

// Round 3
// 4797.164 us; speedup vs baseline: 1.5075x; 1.5075x over previous
//
#include <hip/hip_runtime.h>

#define Bb 256
#define Tt 256
#define Dd 64
#define Hh 512
#define BH (Bb*Hh)

typedef _Float16 half8 __attribute__((ext_vector_type(8)));
typedef float floatx4 __attribute__((ext_vector_type(4)));

__device__ __forceinline__ float sigm(float x) { return 1.0f/(1.0f + __expf(-x)); }
__device__ __forceinline__ float tanh_(float x) {
  if (x >  15.0f) return  1.0f;
  if (x < -15.0f) return -1.0f;
  float e = __expf(2.0f*x);
  return (e - 1.0f)/(e + 1.0f);
}

// ws layout: xf16[T*B*D] | h1[3*BH] | h2[2*BH] | flags[512]
// flags (uints, 128B-spaced): bar_grp[g] at g*32, prog[g] at (8+g)*32
__global__ void init_kernel(const float* __restrict__ x,
                            _Float16* __restrict__ xf16,
                            _Float16* __restrict__ hz,
                            unsigned* __restrict__ flags) {
  const int j0 = blockIdx.x*blockDim.x + threadIdx.x;
  if (j0 < 512) flags[j0] = 0u;
  const int NX = Bb*Tt*Dd;          // 4194304
  const int NZ = 5*BH;              // h1 x3 + h2 x2
  for (int j = j0; j < NX + NZ; j += gridDim.x*blockDim.x) {
    if (j < NX) {
      int t = j >> 14, r = j & 16383;
      int b = r >> 6, d = r & 63;
      xf16[j] = (_Float16)x[(b << 14) + (t << 6) + d];
    } else {
      hz[j - NX] = (_Float16)0.0f;
    }
  }
}

__global__ void __launch_bounds__(256, 1)
lstm_fused(const _Float16* __restrict__ xf16,
           _Float16* __restrict__ hbufs,      // h1[3 x BH] then h2[2 x BH]
           unsigned* __restrict__ flags,
           const float* __restrict__ Wih0, const float* __restrict__ Whh0,
           const float* __restrict__ bih0, const float* __restrict__ bhh0,
           const float* __restrict__ Wih1, const float* __restrict__ Whh1,
           const float* __restrict__ bih1, const float* __restrict__ bhh1,
           const float* __restrict__ fcw,  const float* __restrict__ fcb,
           float* __restrict__ out)
{
  extern __shared__ _Float16 lds[];   // 64 gate-rows x 1024 k x 2B = 128 KiB, k XOR-swizzled

  const int tid = threadIdx.x;
  const int bid = blockIdx.x;
  const int grp = bid & 7;            // (layer,rgi) group == XCD (heuristic only)
  const int lb  = grp >> 2;           // layer
  const int rgi = grp & 3;            // batch row-group (64 rows)
  const int cgi = bid >> 3;           // 0..31 col-group (16 h-cols)
  const int hc0 = cgi * 16;
  const int r0  = rgi * 64;

  unsigned* const barg  = flags + grp*32;
  unsigned* const progs = flags + (8 + grp)*32;
  unsigned* const progp = flags + (8 + (grp ^ 4))*32;

  _Float16* const h1buf = hbufs;            // 3 slots
  _Float16* const h2buf = hbufs + 3*BH;     // 2 slots

  // ---- preload W slice (fp32 -> fp16), swizzled ----
  // gate-row gr = tile*16 + s; tiles: {0:i/f hc0-7}{1:g/o hc0-7}{2:i/f hc8-15}{3:g/o hc8-15}
  {
    const float* Whh = lb ? Whh1 : Whh0;
    const float* Wih = lb ? Wih1 : Wih0;
    const int Kin = lb ? Hh : Dd;
    for (int gr = 0; gr < 64; ++gr) {
      const int t = gr >> 4, s = gr & 15;
      const int gate = (t & 1)*2 + (s >> 3);       // 0=i,1=f,2=g,3=o
      const int hcc  = (t >> 1)*8 + (s & 7);
      const int wrow = gate*Hh + hc0 + hcc;
      const int swz  = (s & 7) << 3;
      const float* s0 = Whh + (size_t)wrow*Hh;
      for (int k = tid; k < Hh; k += 256)
        lds[(size_t)gr*1024 + (k ^ swz)] = (_Float16)s0[k];
      const float* s1 = Wih + (size_t)wrow*Kin;
      for (int k = tid; k < Kin; k += 256)
        lds[(size_t)gr*1024 + ((512 + k) ^ swz)] = (_Float16)s1[k];
    }
  }
  __syncthreads();

  // lane geometry: wave tile = 32 rows x 32 gate-cols
  const int w    = tid >> 6;
  const int lane = tid & 63;
  const int wr   = w >> 1;          // row half of block tile
  const int wc   = w & 1;           // col half (wc=0: h-cols 0-7; wc=1: 8-15)
  const int kg   = lane >> 4;
  const int n15  = lane & 15;
  const bool lo  = (n15 < 8);
  const int xr   = (n15 & 7) << 3;
  const int hcol = hc0 + wc*8 + (n15 & 7);
  const int rowb = r0 + wr*32;

  const _Float16* const b0base = lds + (size_t)(wc*32 + n15)*1024;
  const _Float16* const b1base = lds + (size_t)(wc*32 + 16 + n15)*1024;

  const float* bi = lb ? bih1 : bih0;
  const float* bh = lb ? bhh1 : bhh0;
  const float biasA = lo ? (bi[hcol]      + bh[hcol])      : (bi[512+hcol]  + bh[512+hcol]);   // i | f
  const float biasB = lo ? (bi[1024+hcol] + bh[1024+hcol]) : (bi[1536+hcol] + bh[1536+hcol]);  // g | o

  float cst[2][4] = {{0.f,0.f,0.f,0.f},{0.f,0.f,0.f,0.f}};

  for (int i = 0; i <= Tt; ++i) {
    const bool active = lb ? (i >= 1) : (i < Tt);
    if (active) {
      // cross-group wait (producer/consumer epochs, 2-deep via triple-buffered h1)
      if (tid == 0) {
        if (lb) {
          // need layer0 finished iter i-1 (timestep i-1 in slot (i-1)%3): prog0 >= i
          while (__hip_atomic_load(progp, __ATOMIC_RELAXED, __HIP_MEMORY_SCOPE_AGENT) < (unsigned)i)
            __builtin_amdgcn_s_sleep(2);
        } else if (i >= 3) {
          // about to overwrite h1 timestep i-3 (slot i%3), read by layer1 at iter i-2:
          // need layer1 finished iter i-2: prog1 >= i-1
          while (__hip_atomic_load(progp, __ATOMIC_RELAXED, __HIP_MEMORY_SCOPE_AGENT) < (unsigned)(i-1))
            __builtin_amdgcn_s_sleep(2);
        }
        __builtin_amdgcn_fence(__ATOMIC_ACQUIRE, "agent");
      }
      __syncthreads();

      const _Float16* hprev; _Float16* hcur; const _Float16* src2;
      if (lb) {
        hprev = h2buf + (size_t)((i+1)&1)*BH;
        hcur  = h2buf + (size_t)(i&1)*BH;
        src2  = h1buf + (size_t)((i+2)%3)*BH;   // layer0 timestep i-1
      } else {
        hprev = h1buf + (size_t)((i+2)%3)*BH;   // own timestep i-1 ((i-1)%3)
        hcur  = h1buf + (size_t)(i%3)*BH;
        src2  = xf16 + (size_t)i*(Bb*Dd);
      }

      floatx4 acc[2][2] = {};

      if (lb) {
        half8 a1[2][16], a2[2][16];
        #pragma unroll
        for (int rs = 0; rs < 2; ++rs)
          #pragma unroll
          for (int ks = 0; ks < 16; ++ks) {
            a1[rs][ks] = *(const half8*)(hprev + (size_t)(rowb + rs*16 + n15)*Hh + 8*kg + 32*ks);
            a2[rs][ks] = *(const half8*)(src2  + (size_t)(rowb + rs*16 + n15)*Hh + 8*kg + 32*ks);
          }
        #pragma unroll
        for (int ks = 0; ks < 16; ++ks) {
          const half8 b0 = *(const half8*)(b0base + ((32*ks + 8*kg) ^ xr));
          const half8 b1 = *(const half8*)(b1base + ((32*ks + 8*kg) ^ xr));
          acc[0][0] = __builtin_amdgcn_mfma_f32_16x16x32_f16(a1[0][ks], b0, acc[0][0], 0,0,0);
          acc[0][1] = __builtin_amdgcn_mfma_f32_16x16x32_f16(a1[0][ks], b1, acc[0][1], 0,0,0);
          acc[1][0] = __builtin_amdgcn_mfma_f32_16x16x32_f16(a1[1][ks], b0, acc[1][0], 0,0,0);
          acc[1][1] = __builtin_amdgcn_mfma_f32_16x16x32_f16(a1[1][ks], b1, acc[1][1], 0,0,0);
        }
        #pragma unroll
        for (int ks = 0; ks < 16; ++ks) {
          const half8 b0 = *(const half8*)(b0base + ((512 + 32*ks + 8*kg) ^ xr));
          const half8 b1 = *(const half8*)(b1base + ((512 + 32*ks + 8*kg) ^ xr));
          acc[0][0] = __builtin_amdgcn_mfma_f32_16x16x32_f16(a2[0][ks], b0, acc[0][0], 0,0,0);
          acc[0][1] = __builtin_amdgcn_mfma_f32_16x16x32_f16(a2[0][ks], b1, acc[0][1], 0,0,0);
          acc[1][0] = __builtin_amdgcn_mfma_f32_16x16x32_f16(a2[1][ks], b0, acc[1][0], 0,0,0);
          acc[1][1] = __builtin_amdgcn_mfma_f32_16x16x32_f16(a2[1][ks], b1, acc[1][1], 0,0,0);
        }
      } else {
        half8 a1[2][16], a2[2][2];
        #pragma unroll
        for (int rs = 0; rs < 2; ++rs) {
          #pragma unroll
          for (int ks = 0; ks < 16; ++ks)
            a1[rs][ks] = *(const half8*)(hprev + (size_t)(rowb + rs*16 + n15)*Hh + 8*kg + 32*ks);
          #pragma unroll
          for (int ks = 0; ks < 2; ++ks)
            a2[rs][ks] = *(const half8*)(src2 + (size_t)(rowb + rs*16 + n15)*Dd + 8*kg + 32*ks);
        }
        #pragma unroll
        for (int ks = 0; ks < 16; ++ks) {
          const half8 b0 = *(const half8*)(b0base + ((32*ks + 8*kg) ^ xr));
          const half8 b1 = *(const half8*)(b1base + ((32*ks + 8*kg) ^ xr));
          acc[0][0] = __builtin_amdgcn_mfma_f32_16x16x32_f16(a1[0][ks], b0, acc[0][0], 0,0,0);
          acc[0][1] = __builtin_amdgcn_mfma_f32_16x16x32_f16(a1[0][ks], b1, acc[0][1], 0,0,0);
          acc[1][0] = __builtin_amdgcn_mfma_f32_16x16x32_f16(a1[1][ks], b0, acc[1][0], 0,0,0);
          acc[1][1] = __builtin_amdgcn_mfma_f32_16x16x32_f16(a1[1][ks], b1, acc[1][1], 0,0,0);
        }
        #pragma unroll
        for (int ks = 0; ks < 2; ++ks) {
          const half8 b0 = *(const half8*)(b0base + ((512 + 32*ks + 8*kg) ^ xr));
          const half8 b1 = *(const half8*)(b1base + ((512 + 32*ks + 8*kg) ^ xr));
          acc[0][0] = __builtin_amdgcn_mfma_f32_16x16x32_f16(a2[0][ks], b0, acc[0][0], 0,0,0);
          acc[0][1] = __builtin_amdgcn_mfma_f32_16x16x32_f16(a2[0][ks], b1, acc[0][1], 0,0,0);
          acc[1][0] = __builtin_amdgcn_mfma_f32_16x16x32_f16(a2[1][ks], b0, acc[1][0], 0,0,0);
          acc[1][1] = __builtin_amdgcn_mfma_f32_16x16x32_f16(a2[1][ks], b1, acc[1][1], 0,0,0);
        }
      }

      // pointwise: lo lanes hold i,g; hi lanes f,o for same h-col (lane^8)
      #pragma unroll
      for (int rs = 0; rs < 2; ++rs) {
        #pragma unroll
        for (int rr = 0; rr < 4; ++rr) {
          const float pA = acc[rs][0][rr] + biasA;
          const float pB = acc[rs][1][rr] + biasB;
          const float v1 = sigm(pA);                    // sig(i) | sig(f)
          const float v2 = lo ? tanh_(pB) : sigm(pB);   // tanh(g) | sig(o)
          const float fs  = __shfl_xor(v1, 8, 64);
          const float os_ = __shfl_xor(v2, 8, 64);
          if (lo) {
            const float c = fs * cst[rs][rr] + v1 * v2;
            cst[rs][rr] = c;
            const float hval = os_ * tanh_(c);
            const int row = rowb + rs*16 + kg*4 + rr;
            hcur[(size_t)row*Hh + hcol] = (_Float16)hval;
          }
        }
      }
    }

    // intra-group barrier (32 blocks); last arriver publishes epoch i+1
    __syncthreads();
    if (tid == 0) {
      const unsigned tgt = 32u*(unsigned)(i+1);
      unsigned old = __hip_atomic_fetch_add(barg, 1u, __ATOMIC_ACQ_REL, __HIP_MEMORY_SCOPE_AGENT);
      if (old == tgt - 1u) {
        __hip_atomic_store(progs, (unsigned)(i+1), __ATOMIC_RELEASE, __HIP_MEMORY_SCOPE_AGENT);
      } else {
        while (__hip_atomic_load(barg, __ATOMIC_RELAXED, __HIP_MEMORY_SCOPE_AGENT) < tgt)
          __builtin_amdgcn_s_sleep(1);
      }
      __builtin_amdgcn_fence(__ATOMIC_ACQUIRE, "agent");
    }
    __syncthreads();
  }

  // FC: out[b] = h2_final[b,:] . fcw + fcb   (layer1 last writes at i=256, parity 0)
  if (bid == 0) {
    if (tid == 0) {
      for (int g = 4; g < 8; ++g) {
        unsigned* pg = flags + (8 + g)*32;
        while (__hip_atomic_load(pg, __ATOMIC_RELAXED, __HIP_MEMORY_SCOPE_AGENT) < (unsigned)(Tt+1))
          __builtin_amdgcn_s_sleep(2);
      }
      __builtin_amdgcn_fence(__ATOMIC_ACQUIRE, "agent");
    }
    __syncthreads();
    const int b = tid;
    const _Float16* h2 = h2buf;
    float acc = fcb[0];
    #pragma unroll 8
    for (int k = 0; k < 512; ++k)
      acc += (float)h2[(size_t)b*512 + k] * fcw[k];
    out[b] = acc;
  }
}

extern "C" void kernel_launch(void* const* d_in, const int* in_sizes, int n_in,
                              void* d_out, int out_size, void* d_ws, size_t ws_size,
                              hipStream_t stream) {
  const float* x    = (const float*)d_in[0];
  const float* Wih0 = (const float*)d_in[1];
  const float* Whh0 = (const float*)d_in[2];
  const float* bih0 = (const float*)d_in[3];
  const float* bhh0 = (const float*)d_in[4];
  const float* Wih1 = (const float*)d_in[5];
  const float* Whh1 = (const float*)d_in[6];
  const float* bih1 = (const float*)d_in[7];
  const float* bhh1 = (const float*)d_in[8];
  const float* fcw  = (const float*)d_in[9];
  const float* fcb  = (const float*)d_in[10];
  float* out = (float*)d_out;

  _Float16* xf16  = (_Float16*)d_ws;                         // 8,388,608 B
  _Float16* hbufs = xf16 + (size_t)Bb*Tt*Dd;                 // 5*BH halfs = 1.25 MiB
  unsigned* flags = (unsigned*)(hbufs + (size_t)5*BH);       // 2 KiB

  hipFuncSetAttribute((const void*)lstm_fused,
                      hipFuncAttributeMaxDynamicSharedMemorySize, 131072);

  hipLaunchKernelGGL(init_kernel, dim3(1024), dim3(256), 0, stream, x, xf16, hbufs, flags);

  hipLaunchKernelGGL(lstm_fused, dim3(256), dim3(256), 131072, stream,
                     (const _Float16*)xf16, hbufs, flags,
                     Wih0, Whh0, bih0, bhh0, Wih1, Whh1, bih1, bhh1, fcw, fcb, out);
}

// Round 5
// 3481.179 us; speedup vs baseline: 2.0774x; 1.3780x over previous
//
#include <hip/hip_runtime.h>

#define Bb 256
#define Tt 256
#define Dd 64
#define Hh 512
#define BH (Bb*Hh)

typedef _Float16 half8 __attribute__((ext_vector_type(8)));
typedef float floatx4 __attribute__((ext_vector_type(4)));
typedef unsigned long long u64x2 __attribute__((ext_vector_type(2)));

__device__ __forceinline__ float sigm(float x) { return 1.0f/(1.0f + __expf(-x)); }
__device__ __forceinline__ float tanh_(float x) {
  if (x >  15.0f) return  1.0f;
  if (x < -15.0f) return -1.0f;
  float e = __expf(2.0f*x);
  return (e - 1.0f)/(e + 1.0f);
}

// Coherent (fabric/L3-point) accesses: relaxed system-scope atomics -> sc0 sc1,
// compiler-managed (no manual waitcnt on loads, no cache-wide fences anywhere).
__device__ __forceinline__ half8 ld_h8(const _Float16* p) {
  u64x2 t;
  t.x = __hip_atomic_load((const unsigned long long*)p,       __ATOMIC_RELAXED, __HIP_MEMORY_SCOPE_SYSTEM);
  t.y = __hip_atomic_load(((const unsigned long long*)p) + 1, __ATOMIC_RELAXED, __HIP_MEMORY_SCOPE_SYSTEM);
  return __builtin_bit_cast(half8, t);
}
__device__ __forceinline__ void st_half(_Float16* p, float vf) {
  unsigned short b = __builtin_bit_cast(unsigned short, (_Float16)vf);
  __hip_atomic_store((unsigned short*)p, b, __ATOMIC_RELAXED, __HIP_MEMORY_SCOPE_SYSTEM);
}
__device__ __forceinline__ unsigned ld_flag(const unsigned* p) {
  return __hip_atomic_load(p, __ATOMIC_RELAXED, __HIP_MEMORY_SCOPE_SYSTEM);
}
__device__ __forceinline__ void st_flag(unsigned* p, unsigned v) {
  __hip_atomic_store(p, v, __ATOMIC_RELAXED, __HIP_MEMORY_SCOPE_SYSTEM);
}

// ws layout: xf16[T*B*D] | h1[3*BH] | h2[2*BH] | flags[512]
// flags[g*32 + cgi]: epoch flag of block (group g, col-group cgi)
__global__ void init_kernel(const float* __restrict__ x,
                            _Float16* __restrict__ xf16,
                            _Float16* __restrict__ hz,
                            unsigned* __restrict__ flags) {
  const int j0 = blockIdx.x*blockDim.x + threadIdx.x;
  if (j0 < 512) flags[j0] = 0u;
  const int NX = Bb*Tt*Dd;          // 4194304
  const int NZ = 5*BH;              // h1 x3 + h2 x2
  for (int j = j0; j < NX + NZ; j += gridDim.x*blockDim.x) {
    if (j < NX) {
      int t = j >> 14, r = j & 16383;
      int b = r >> 6, d = r & 63;
      xf16[j] = (_Float16)x[(b << 14) + (t << 6) + d];
    } else {
      hz[j - NX] = (_Float16)0.0f;
    }
  }
}

__global__ void __launch_bounds__(256, 1)
lstm_fused(const _Float16* __restrict__ xf16,
           _Float16* __restrict__ hbufs,      // h1[3 x BH] then h2[2 x BH]
           unsigned* __restrict__ flags,
           const float* __restrict__ Wih0, const float* __restrict__ Whh0,
           const float* __restrict__ bih0, const float* __restrict__ bhh0,
           const float* __restrict__ Wih1, const float* __restrict__ Whh1,
           const float* __restrict__ bih1, const float* __restrict__ bhh1,
           const float* __restrict__ fcw,  const float* __restrict__ fcb,
           float* __restrict__ out)
{
  extern __shared__ _Float16 lds[];   // 64 gate-rows x 1024 k x 2B = 128 KiB, k XOR-swizzled

  const int tid = threadIdx.x;
  const int bid = blockIdx.x;
  const int grp = bid & 7;            // (layer,rgi) group (XCD-locality heuristic only)
  const int lb  = grp >> 2;           // layer
  const int rgi = grp & 3;            // batch row-group (64 rows)
  const int cgi = bid >> 3;           // 0..31 col-group (16 h-cols)
  const int hc0 = cgi * 16;
  const int r0  = rgi * 64;

  unsigned* const myflag = flags + grp*32 + cgi;

  _Float16* const h1buf = hbufs;            // 3 slots
  _Float16* const h2buf = hbufs + 3*BH;     // 2 slots

  // ---- preload W slice (fp32 -> fp16), swizzled ----
  // gate-row gr = tile*16 + s; tiles: {0:i/f hc0-7}{1:g/o hc0-7}{2:i/f hc8-15}{3:g/o hc8-15}
  {
    const float* Whh = lb ? Whh1 : Whh0;
    const float* Wih = lb ? Wih1 : Wih0;
    const int Kin = lb ? Hh : Dd;
    for (int gr = 0; gr < 64; ++gr) {
      const int t = gr >> 4, s = gr & 15;
      const int gate = (t & 1)*2 + (s >> 3);       // 0=i,1=f,2=g,3=o
      const int hcc  = (t >> 1)*8 + (s & 7);
      const int wrow = gate*Hh + hc0 + hcc;
      const int swz  = (s & 7) << 3;
      const float* s0 = Whh + (size_t)wrow*Hh;
      for (int k = tid; k < Hh; k += 256)
        lds[(size_t)gr*1024 + (k ^ swz)] = (_Float16)s0[k];
      const float* s1 = Wih + (size_t)wrow*Kin;
      for (int k = tid; k < Kin; k += 256)
        lds[(size_t)gr*1024 + ((512 + k) ^ swz)] = (_Float16)s1[k];
    }
  }
  __syncthreads();

  // lane geometry: wave tile = 16 rows x all 64 gate-cols (4 b-tiles), rows disjoint per wave
  const int w    = tid >> 6;
  const int lane = tid & 63;
  const int kg   = lane >> 4;
  const int n15  = lane & 15;
  const bool lo  = (n15 < 8);
  const int xr   = (n15 & 7) << 3;
  const int rowb = r0 + w*16;          // wave's 16 rows: rowb..rowb+15 (A row = rowb + n15)

  const float* bi = lb ? bih1 : bih0;
  const float* bh = lb ? bhh1 : bhh0;
  float biasA[2], biasB[2];            // per hcol-octet: A = i|f, B = g|o
  #pragma unroll
  for (int o = 0; o < 2; ++o) {
    const int hc = hc0 + o*8 + (n15 & 7);
    biasA[o] = lo ? (bi[hc]      + bh[hc])      : (bi[512+hc]  + bh[512+hc]);
    biasB[o] = lo ? (bi[1024+hc] + bh[1024+hc]) : (bi[1536+hc] + bh[1536+hc]);
  }

  float cst[2][4] = {{0.f,0.f,0.f,0.f},{0.f,0.f,0.f,0.f}};

  for (int i = 0; i <= Tt; ++i) {
    const bool active = lb ? (i >= 1) : (i < Tt);
    if (active) {
      // ---- acquire: poll peers' epoch flags ----
      if (tid < 64) {
        const int gsel = (tid < 32) ? grp : (grp ^ 4);
        const unsigned tgt = (tid < 32) ? (unsigned)i
                            : (lb ? (unsigned)i : (unsigned)(i >= 3 ? i - 1 : 0));
        const unsigned* fp = flags + gsel*32 + (tid & 31);
        while (!__all((int)(ld_flag(fp) >= tgt)))
          __builtin_amdgcn_s_sleep(2);
      }
      __syncthreads();
      asm volatile("" ::: "memory");            // no hoisting of h loads above the poll
      __builtin_amdgcn_sched_barrier(0);

      const _Float16* hprev; _Float16* hcur; const _Float16* src2;
      if (lb) {
        hprev = h2buf + (size_t)((i+1)&1)*BH;
        hcur  = h2buf + (size_t)(i&1)*BH;
        src2  = h1buf + (size_t)((i+2)%3)*BH;   // layer0 timestep i-1
      } else {
        hprev = h1buf + (size_t)((i+2)%3)*BH;   // own timestep i-1
        hcur  = h1buf + (size_t)(i%3)*BH;
        src2  = xf16 + (size_t)i*(Bb*Dd);
      }

      floatx4 acc[4] = {};   // b-tiles: 0=i/f oct0, 1=g/o oct0, 2=i/f oct1, 3=g/o oct1
      const _Float16* const arow = hprev + (size_t)(rowb + n15)*Hh + 8*kg;

      if (lb) {
        half8 a1[16], a2[16];
        const _Float16* const crow = src2 + (size_t)(rowb + n15)*Hh + 8*kg;
        #pragma unroll
        for (int ks = 0; ks < 16; ++ks) a1[ks] = ld_h8(arow + 32*ks);
        #pragma unroll
        for (int ks = 0; ks < 16; ++ks) a2[ks] = ld_h8(crow + 32*ks);
        #pragma unroll
        for (int ks = 0; ks < 16; ++ks)
          #pragma unroll
          for (int bt = 0; bt < 4; ++bt) {
            const half8 b = *(const half8*)(lds + (size_t)(bt*16 + n15)*1024 + ((32*ks + 8*kg) ^ xr));
            acc[bt] = __builtin_amdgcn_mfma_f32_16x16x32_f16(a1[ks], b, acc[bt], 0,0,0);
          }
        #pragma unroll
        for (int ks = 0; ks < 16; ++ks)
          #pragma unroll
          for (int bt = 0; bt < 4; ++bt) {
            const half8 b = *(const half8*)(lds + (size_t)(bt*16 + n15)*1024 + ((512 + 32*ks + 8*kg) ^ xr));
            acc[bt] = __builtin_amdgcn_mfma_f32_16x16x32_f16(a2[ks], b, acc[bt], 0,0,0);
          }
      } else {
        half8 a1[16], a2[2];
        const _Float16* const crow = src2 + (size_t)(rowb + n15)*Dd + 8*kg;
        #pragma unroll
        for (int ks = 0; ks < 16; ++ks) a1[ks] = ld_h8(arow + 32*ks);
        #pragma unroll
        for (int ks = 0; ks < 2; ++ks)  a2[ks] = *(const half8*)(crow + 32*ks);  // x: normal cached
        #pragma unroll
        for (int ks = 0; ks < 16; ++ks)
          #pragma unroll
          for (int bt = 0; bt < 4; ++bt) {
            const half8 b = *(const half8*)(lds + (size_t)(bt*16 + n15)*1024 + ((32*ks + 8*kg) ^ xr));
            acc[bt] = __builtin_amdgcn_mfma_f32_16x16x32_f16(a1[ks], b, acc[bt], 0,0,0);
          }
        #pragma unroll
        for (int ks = 0; ks < 2; ++ks)
          #pragma unroll
          for (int bt = 0; bt < 4; ++bt) {
            const half8 b = *(const half8*)(lds + (size_t)(bt*16 + n15)*1024 + ((512 + 32*ks + 8*kg) ^ xr));
            acc[bt] = __builtin_amdgcn_mfma_f32_16x16x32_f16(a2[ks], b, acc[bt], 0,0,0);
          }
      }

      // pointwise: lanes n15<8 hold i,g; n15>=8 hold f,o for same h-col (pair via lane^8)
      #pragma unroll
      for (int o = 0; o < 2; ++o) {
        #pragma unroll
        for (int rr = 0; rr < 4; ++rr) {
          const float pA = acc[2*o][rr]   + biasA[o];
          const float pB = acc[2*o+1][rr] + biasB[o];
          const float v1 = sigm(pA);                    // sig(i) | sig(f)
          const float v2 = lo ? tanh_(pB) : sigm(pB);   // tanh(g) | sig(o)
          const float fs  = __shfl_xor(v1, 8, 64);
          const float os_ = __shfl_xor(v2, 8, 64);
          if (lo) {
            const float c = fs * cst[o][rr] + v1 * v2;
            cst[o][rr] = c;
            const float hval = os_ * tanh_(c);
            const int row = rowb + kg*4 + rr;           // C/D: row=(lane>>4)*4+reg
            const int col = hc0 + o*8 + (n15 & 7);
            st_half(hcur + (size_t)row*Hh + col, hval);
          }
        }
      }
    }

    // ---- release: drain h stores (write-through), block sync, publish epoch ----
    asm volatile("s_waitcnt vmcnt(0)" ::: "memory");
    __syncthreads();
    if (tid == 0) st_flag(myflag, (unsigned)(i + 1));
  }

  // FC: out[b] = h2_final[b,:] . fcw + fcb   (layer1 last writes at i=256 -> slot 0)
  if (bid == 0) {
    if (tid < 64) {
      const unsigned* f1 = flags + (4 + (tid >> 5))*32 + (tid & 31);  // groups 4,5
      const unsigned* f2 = f1 + 64;                                    // groups 6,7
      while (true) {
        int ok = (ld_flag(f1) > (unsigned)Tt) & (ld_flag(f2) > (unsigned)Tt);
        if (__all(ok)) break;
        __builtin_amdgcn_s_sleep(2);
      }
    }
    __syncthreads();
    asm volatile("" ::: "memory");
    const _Float16* h2 = h2buf;
    float acc = fcb[0];
    for (int c = 0; c < 4; ++c) {
      half8 v[16];
      #pragma unroll
      for (int j = 0; j < 16; ++j)
        v[j] = ld_h8(h2 + (size_t)tid*Hh + c*128 + j*8);
      #pragma unroll
      for (int j = 0; j < 16; ++j)
        #pragma unroll
        for (int e = 0; e < 8; ++e)
          acc += (float)v[j][e] * fcw[c*128 + j*8 + e];
    }
    out[tid] = acc;
  }
}

extern "C" void kernel_launch(void* const* d_in, const int* in_sizes, int n_in,
                              void* d_out, int out_size, void* d_ws, size_t ws_size,
                              hipStream_t stream) {
  const float* x    = (const float*)d_in[0];
  const float* Wih0 = (const float*)d_in[1];
  const float* Whh0 = (const float*)d_in[2];
  const float* bih0 = (const float*)d_in[3];
  const float* bhh0 = (const float*)d_in[4];
  const float* Wih1 = (const float*)d_in[5];
  const float* Whh1 = (const float*)d_in[6];
  const float* bih1 = (const float*)d_in[7];
  const float* bhh1 = (const float*)d_in[8];
  const float* fcw  = (const float*)d_in[9];
  const float* fcb  = (const float*)d_in[10];
  float* out = (float*)d_out;

  _Float16* xf16  = (_Float16*)d_ws;                         // 8,388,608 B
  _Float16* hbufs = xf16 + (size_t)Bb*Tt*Dd;                 // 5*BH halfs
  unsigned* flags = (unsigned*)(hbufs + (size_t)5*BH);       // 2 KiB

  hipFuncSetAttribute((const void*)lstm_fused,
                      hipFuncAttributeMaxDynamicSharedMemorySize, 131072);

  hipLaunchKernelGGL(init_kernel, dim3(1024), dim3(256), 0, stream, x, xf16, hbufs, flags);

  hipLaunchKernelGGL(lstm_fused, dim3(256), dim3(256), 131072, stream,
                     (const _Float16*)xf16, hbufs, flags,
                     Wih0, Whh0, bih0, bhh0, Wih1, Whh1, bih1, bhh1, fcw, fcb, out);
}

// Round 6
// 3178.729 us; speedup vs baseline: 2.2750x; 1.0951x over previous
//
#include <hip/hip_runtime.h>

#define Bb 256
#define Tt 256
#define Dd 64
#define Hh 512
#define BH (Bb*Hh)
#define S1 4                       // h1 slots (L0 run-ahead slack)

typedef _Float16 half8 __attribute__((ext_vector_type(8)));
typedef float floatx4 __attribute__((ext_vector_type(4)));
typedef unsigned long long u64x2 __attribute__((ext_vector_type(2)));

__device__ __forceinline__ float sigm(float x) { return 1.0f/(1.0f + __expf(-x)); }
__device__ __forceinline__ float tanh_(float x) {
  if (x >  15.0f) return  1.0f;
  if (x < -15.0f) return -1.0f;
  float e = __expf(2.0f*x);
  return (e - 1.0f)/(e + 1.0f);
}

// Coherent (fabric/L3-point) accesses: relaxed system-scope atomics -> sc0 sc1,
// compiler-managed (correct waitcnts/spills), no cache-wide fences anywhere.
__device__ __forceinline__ half8 ld_h8(const _Float16* p) {
  u64x2 t;
  t.x = __hip_atomic_load((const unsigned long long*)p,       __ATOMIC_RELAXED, __HIP_MEMORY_SCOPE_SYSTEM);
  t.y = __hip_atomic_load(((const unsigned long long*)p) + 1, __ATOMIC_RELAXED, __HIP_MEMORY_SCOPE_SYSTEM);
  return __builtin_bit_cast(half8, t);
}
__device__ __forceinline__ void st_u64(_Float16* p, unsigned long long v) {
  __hip_atomic_store((unsigned long long*)p, v, __ATOMIC_RELAXED, __HIP_MEMORY_SCOPE_SYSTEM);
}
__device__ __forceinline__ unsigned ld_flag(const unsigned* p) {
  return __hip_atomic_load(p, __ATOMIC_RELAXED, __HIP_MEMORY_SCOPE_SYSTEM);
}
__device__ __forceinline__ void st_flag(unsigned* p, unsigned v) {
  __hip_atomic_store(p, v, __ATOMIC_RELAXED, __HIP_MEMORY_SCOPE_SYSTEM);
}

// ws layout: xf16[T*B*D] | h1[S1*BH] | h2[2*BH] | flags[512]
// flags[g*32 + cgi]: epoch flag of block (group g, col-group cgi)
__global__ void init_kernel(const float* __restrict__ x,
                            _Float16* __restrict__ xf16,
                            _Float16* __restrict__ hz,
                            unsigned* __restrict__ flags) {
  const int j0 = blockIdx.x*blockDim.x + threadIdx.x;
  if (j0 < 512) flags[j0] = 0u;
  const int NX = Bb*Tt*Dd;          // 4194304
  const int NZ = (S1+2)*BH;         // h1 x S1 + h2 x2
  for (int j = j0; j < NX + NZ; j += gridDim.x*blockDim.x) {
    if (j < NX) {
      int t = j >> 14, r = j & 16383;
      int b = r >> 6, d = r & 63;
      xf16[j] = (_Float16)x[(b << 14) + (t << 6) + d];
    } else {
      hz[j - NX] = (_Float16)0.0f;
    }
  }
}

__global__ void __launch_bounds__(256, 1)
lstm_fused(const _Float16* __restrict__ xf16,
           _Float16* __restrict__ hbufs,      // h1[S1 x BH] then h2[2 x BH]
           unsigned* __restrict__ flags,
           const float* __restrict__ Wih0, const float* __restrict__ Whh0,
           const float* __restrict__ bih0, const float* __restrict__ bhh0,
           const float* __restrict__ Wih1, const float* __restrict__ Whh1,
           const float* __restrict__ bih1, const float* __restrict__ bhh1,
           const float* __restrict__ fcw,  const float* __restrict__ fcb,
           float* __restrict__ out)
{
  // LDS: W in MFMA-fragment-major order: group g=(ks*4+bt) holds 512 halfs,
  // lane (n15,kg) owns halfs [(n15*4+kg)*8 .. +7] = W[gaterow(bt,n15)][k=32ks+8kg+e].
  // 65536 halfs W + 4 waves x 256 halfs h-store staging = 133120 B total.
  extern __shared__ _Float16 lds[];

  const int tid = threadIdx.x;
  const int bid = blockIdx.x;
  const int grp = bid & 7;            // (layer,rgi) group
  const int lb  = grp >> 2;           // layer
  const int rgi = grp & 3;            // batch row-group (64 rows)
  const int cgi = bid >> 3;           // 0..31 col-group (16 h-cols)
  const int hc0 = cgi * 16;
  const int r0  = rgi * 64;

  unsigned* const myflag = flags + grp*32 + cgi;

  _Float16* const h1buf = hbufs;            // S1 slots
  _Float16* const h2buf = hbufs + S1*BH;    // 2 slots

  // ---- preload W slice (fp32 -> fp16) into fragment-major LDS ----
  {
    const float* Whh = lb ? Whh1 : Whh0;
    const float* Wih = lb ? Wih1 : Wih0;
    const int Kin = lb ? Hh : Dd;
    const int KT  = Hh + Kin;                 // valid k_total range
    for (int idx = tid; idx < 64*KT; idx += 256) {
      const int gr = idx / KT;
      const int k  = idx - gr*KT;
      const int bt = gr >> 4, s = gr & 15;
      const int gate = (bt & 1)*2 + (s >> 3);           // 0=i,1=f,2=g,3=o
      const int hcc  = (bt >> 1)*8 + (s & 7);
      const int wrow = gate*Hh + hc0 + hcc;
      const float v = (k < Hh) ? Whh[(size_t)wrow*Hh + k]
                               : Wih[(size_t)wrow*Kin + (k - Hh)];
      const int li = (((k >> 5)*4 + bt) << 9) + (((s)*4 + ((k >> 3) & 3)) << 3) + (k & 7);
      lds[li] = (_Float16)v;
    }
  }
  __syncthreads();

  // lane geometry: wave tile = 16 rows x all 64 gate-cols (4 b-tiles)
  const int w    = tid >> 6;
  const int lane = tid & 63;
  const int kg   = lane >> 4;
  const int n15  = lane & 15;
  const bool lo  = (n15 < 8);
  const int rowb = r0 + w*16;              // wave's rows: rowb..rowb+15 (A row = rowb+n15)

  const _Float16* const bfrag = lds + ((n15*4 + kg) << 3);   // + (ks*4+bt)*512
  _Float16* const stage = lds + 65536 + w*256;               // 16 rows x 16 cols

  const float* bi = lb ? bih1 : bih0;
  const float* bh = lb ? bhh1 : bhh0;
  float biasA[2], biasB[2];                // per hcol-octet: A = i|f, B = g|o
  #pragma unroll
  for (int o = 0; o < 2; ++o) {
    const int hc = hc0 + o*8 + (n15 & 7);
    biasA[o] = lo ? (bi[hc]      + bh[hc])      : (bi[512+hc]  + bh[512+hc]);
    biasB[o] = lo ? (bi[1024+hc] + bh[1024+hc]) : (bi[1536+hc] + bh[1536+hc]);
  }

  float cst[2][4] = {{0.f,0.f,0.f,0.f},{0.f,0.f,0.f,0.f}};

  for (int i = 0; i <= Tt; ++i) {
    const bool active = lb ? (i >= 1) : (i < Tt);
    if (active) {
      // ---- acquire: poll epoch flags ----
      // own group >= i (h-self exchange); cross: L1 needs prog0>=i, L0 needs prog1>=i-2 (slot guard)
      if (tid < 64) {
        const int gsel = (tid < 32) ? grp : (grp ^ 4);
        unsigned tgt;
        if (tid < 32)      tgt = (unsigned)i;
        else if (lb)       tgt = (unsigned)i;
        else               tgt = (i >= S1) ? (unsigned)(i - (S1 - 2)) : 0u;
        const unsigned* fp = flags + gsel*32 + (tid & 31);
        while (!__all((int)(ld_flag(fp) >= tgt)))
          __builtin_amdgcn_s_sleep(1);
      }
      __syncthreads();
      asm volatile("" ::: "memory");            // no hoisting of h loads above the poll
      __builtin_amdgcn_sched_barrier(0);

      const _Float16* hprev; _Float16* hcur; const _Float16* src2;
      if (lb) {
        hprev = h2buf + (size_t)((i+1)&1)*BH;
        hcur  = h2buf + (size_t)(i&1)*BH;
        src2  = h1buf + (size_t)((i+S1-1)%S1)*BH;   // layer0 timestep i-1
      } else {
        hprev = h1buf + (size_t)((i+S1-1)%S1)*BH;   // own timestep i-1
        hcur  = h1buf + (size_t)(i%S1)*BH;
        src2  = xf16 + (size_t)i*(Bb*Dd);
      }

      floatx4 acc[4] = {};   // bt: 0=i/f oct0, 1=g/o oct0, 2=i/f oct1, 3=g/o oct1
      const _Float16* const arow = hprev + (size_t)(rowb + n15)*Hh + 8*kg;

      if (lb) {
        half8 a1[16], a2[16];
        const _Float16* const crow = src2 + (size_t)(rowb + n15)*Hh + 8*kg;
        #pragma unroll
        for (int ks = 0; ks < 16; ++ks) a1[ks] = ld_h8(arow + 32*ks);
        #pragma unroll
        for (int ks = 0; ks < 16; ++ks) a2[ks] = ld_h8(crow + 32*ks);
        #pragma unroll
        for (int ks = 0; ks < 16; ++ks)
          #pragma unroll
          for (int bt = 0; bt < 4; ++bt)
            acc[bt] = __builtin_amdgcn_mfma_f32_16x16x32_f16(
                        a1[ks], *(const half8*)(bfrag + ((ks*4 + bt) << 9)), acc[bt], 0,0,0);
        #pragma unroll
        for (int ks = 0; ks < 16; ++ks)
          #pragma unroll
          for (int bt = 0; bt < 4; ++bt)
            acc[bt] = __builtin_amdgcn_mfma_f32_16x16x32_f16(
                        a2[ks], *(const half8*)(bfrag + (((16+ks)*4 + bt) << 9)), acc[bt], 0,0,0);
      } else {
        half8 a1[16], a2[2];
        const _Float16* const crow = src2 + (size_t)(rowb + n15)*Dd + 8*kg;
        #pragma unroll
        for (int ks = 0; ks < 16; ++ks) a1[ks] = ld_h8(arow + 32*ks);
        #pragma unroll
        for (int ks = 0; ks < 2; ++ks)  a2[ks] = *(const half8*)(crow + 32*ks);  // x: cached
        #pragma unroll
        for (int ks = 0; ks < 16; ++ks)
          #pragma unroll
          for (int bt = 0; bt < 4; ++bt)
            acc[bt] = __builtin_amdgcn_mfma_f32_16x16x32_f16(
                        a1[ks], *(const half8*)(bfrag + ((ks*4 + bt) << 9)), acc[bt], 0,0,0);
        #pragma unroll
        for (int ks = 0; ks < 2; ++ks)
          #pragma unroll
          for (int bt = 0; bt < 4; ++bt)
            acc[bt] = __builtin_amdgcn_mfma_f32_16x16x32_f16(
                        a2[ks], *(const half8*)(bfrag + (((16+ks)*4 + bt) << 9)), acc[bt], 0,0,0);
      }

      // pointwise: lanes n15<8 hold i,g; n15>=8 hold f,o (pair via lane^8); stage h in LDS
      #pragma unroll
      for (int o = 0; o < 2; ++o) {
        #pragma unroll
        for (int rr = 0; rr < 4; ++rr) {
          const float pA = acc[2*o][rr]   + biasA[o];
          const float pB = acc[2*o+1][rr] + biasB[o];
          const float v1 = sigm(pA);                    // sig(i) | sig(f)
          const float v2 = lo ? tanh_(pB) : sigm(pB);   // tanh(g) | sig(o)
          const float fs  = __shfl_xor(v1, 8, 64);
          const float os_ = __shfl_xor(v2, 8, 64);
          if (lo) {
            const float c = fs * cst[o][rr] + v1 * v2;
            cst[o][rr] = c;
            const float hval = os_ * tanh_(c);
            stage[(kg*4 + rr)*16 + o*8 + (n15 & 7)] = (_Float16)hval;
          }
        }
      }
      // wave-local staging flush -> one coalesced 8B system store per lane
      asm volatile("s_waitcnt lgkmcnt(0)" ::: "memory");
      __builtin_amdgcn_sched_barrier(0);
      const unsigned long long pk = *(const unsigned long long*)(stage + (lane << 2));
      st_u64(hcur + (size_t)(rowb + (lane >> 2))*Hh + hc0 + (lane & 3)*4, pk);
    }

    // ---- release: drain stores, block sync, publish epoch ----
    asm volatile("s_waitcnt vmcnt(0)" ::: "memory");
    __syncthreads();
    if (tid == 0) st_flag(myflag, (unsigned)(i + 1));
  }

  // FC: out[b] = h2_final[b,:] . fcw + fcb   (layer1 last writes at i=256 -> slot 0)
  if (bid == 0) {
    if (tid < 64) {
      const unsigned* f1 = flags + (4 + (tid >> 5))*32 + (tid & 31);  // groups 4,5
      const unsigned* f2 = f1 + 64;                                    // groups 6,7
      while (true) {
        int ok = (ld_flag(f1) > (unsigned)Tt) & (ld_flag(f2) > (unsigned)Tt);
        if (__all(ok)) break;
        __builtin_amdgcn_s_sleep(1);
      }
    }
    __syncthreads();
    asm volatile("" ::: "memory");
    const _Float16* h2 = h2buf;
    float acc = fcb[0];
    for (int c = 0; c < 4; ++c) {
      half8 v[16];
      #pragma unroll
      for (int j = 0; j < 16; ++j)
        v[j] = ld_h8(h2 + (size_t)tid*Hh + c*128 + j*8);
      #pragma unroll
      for (int j = 0; j < 16; ++j)
        #pragma unroll
        for (int e = 0; e < 8; ++e)
          acc += (float)v[j][e] * fcw[c*128 + j*8 + e];
    }
    out[tid] = acc;
  }
}

extern "C" void kernel_launch(void* const* d_in, const int* in_sizes, int n_in,
                              void* d_out, int out_size, void* d_ws, size_t ws_size,
                              hipStream_t stream) {
  const float* x    = (const float*)d_in[0];
  const float* Wih0 = (const float*)d_in[1];
  const float* Whh0 = (const float*)d_in[2];
  const float* bih0 = (const float*)d_in[3];
  const float* bhh0 = (const float*)d_in[4];
  const float* Wih1 = (const float*)d_in[5];
  const float* Whh1 = (const float*)d_in[6];
  const float* bih1 = (const float*)d_in[7];
  const float* bhh1 = (const float*)d_in[8];
  const float* fcw  = (const float*)d_in[9];
  const float* fcb  = (const float*)d_in[10];
  float* out = (float*)d_out;

  _Float16* xf16  = (_Float16*)d_ws;                         // 8,388,608 B
  _Float16* hbufs = xf16 + (size_t)Bb*Tt*Dd;                 // (S1+2)*BH halfs
  unsigned* flags = (unsigned*)(hbufs + (size_t)(S1+2)*BH);  // 2 KiB

  hipFuncSetAttribute((const void*)lstm_fused,
                      hipFuncAttributeMaxDynamicSharedMemorySize, 133120);

  hipLaunchKernelGGL(init_kernel, dim3(1024), dim3(256), 0, stream, x, xf16, hbufs, flags);

  hipLaunchKernelGGL(lstm_fused, dim3(256), dim3(256), 133120, stream,
                     (const _Float16*)xf16, hbufs, flags,
                     Wih0, Whh0, bih0, bhh0, Wih1, Whh1, bih1, bhh1, fcw, fcb, out);
}